// Round 1
// baseline (300.850 us; speedup 1.0000x reference)
//
#include <hip/hip_runtime.h>

#define B_ 32
#define M_ 8192
#define Q_ 64
#define D_ 128
#define MT 64
#define LDA 136   // bf16 elements per padded row of sA/sC/sU (16B-aligned rows)
#define LDP 72    // bf16 elements per padded row of sP

typedef __attribute__((ext_vector_type(8))) short short8;
typedef __attribute__((ext_vector_type(4))) float floatx4;

__device__ __forceinline__ unsigned short f2bf(float x) {
  union { float f; unsigned u; } t; t.f = x;
  unsigned r = t.u + 0x7fffu + ((t.u >> 16) & 1u);
  return (unsigned short)(r >> 16);
}

// Main kernel: one block handles one (batch, M-chunk). Streams story_a/story_c,
// computes per-row softmax over Q in-register, accumulates c[64][128] in regs.
__global__ __launch_bounds__(256, 2) void memn2n_main(
    const float* __restrict__ A, const float* __restrict__ U,
    const float* __restrict__ Cc, float* __restrict__ dst,
    int chunks, int use_atomic) {
  __shared__ __align__(16) unsigned short sU[Q_ * LDA];
  __shared__ __align__(16) unsigned short sA[MT * LDA];
  __shared__ __align__(16) unsigned short sC[MT * LDA];
  __shared__ __align__(16) unsigned short sP[Q_ * LDP];

  const int tid  = threadIdx.x;
  const int lane = tid & 63;
  const int w    = tid >> 6;        // wave 0..3
  const int l15  = lane & 15;
  const int quad = (lane >> 4) & 3;

  const int blk = blockIdx.x;
  const int b   = blk / chunks;
  const int ch  = blk - b * chunks;
  const int Mc  = M_ / chunks;
  const int m0  = ch * Mc;

  const int g = tid & 31;  // d-group: cols 4g..4g+3
  const int r = tid >> 5;  // row phase: rows r+8i

  // stage u[b] (64x128) -> bf16 LDS, row-major
  const float* ub = U + (size_t)b * Q_ * D_;
#pragma unroll
  for (int i = 0; i < 8; ++i) {
    int row = r + 8 * i;
    float4 v = *(const float4*)(ub + row * D_ + 4 * g);
    ushort4 h = make_ushort4(f2bf(v.x), f2bf(v.y), f2bf(v.z), f2bf(v.w));
    *(ushort4*)&sU[row * LDA + 4 * g] = h;
  }

  floatx4 acc[2][4];
#pragma unroll
  for (int i = 0; i < 2; ++i)
#pragma unroll
    for (int j = 0; j < 4; ++j) acc[i][j] = (floatx4){0.f, 0.f, 0.f, 0.f};

  const float* Abase = A + (size_t)b * M_ * D_ + (size_t)m0 * D_;
  const float* Cbase = Cc + (size_t)b * M_ * D_ + (size_t)m0 * D_;

  const int nT = Mc / MT;
  for (int t = 0; t < nT; ++t) {
    __syncthreads();  // prev iter's GEMM2 done reading sC/sP; sU staged (t==0)
    const float* At = Abase + (size_t)t * MT * D_;
    const float* Ct = Cbase + (size_t)t * MT * D_;
#pragma unroll
    for (int i = 0; i < 8; ++i) {
      int mi = r + 8 * i;
      float4 va = *(const float4*)(At + mi * D_ + 4 * g);
      float4 vc = *(const float4*)(Ct + mi * D_ + 4 * g);
      ushort4 ha = make_ushort4(f2bf(va.x), f2bf(va.y), f2bf(va.z), f2bf(va.w));
      ushort4 hc = make_ushort4(f2bf(vc.x), f2bf(vc.y), f2bf(vc.z), f2bf(vc.w));
      *(ushort4*)&sA[mi * LDA + 4 * g] = ha;
      *(ushort4*)&sC[mi * LDA + 4 * g] = hc;
    }
    __syncthreads();

    // ---- GEMM1: S[m][q] = sum_d A[m][d]*u[q][d]; wave w owns rows 16w..16w+15
    floatx4 s1[4];
#pragma unroll
    for (int qs = 0; qs < 4; ++qs) s1[qs] = (floatx4){0.f, 0.f, 0.f, 0.f};
#pragma unroll
    for (int ks = 0; ks < 4; ++ks) {
      short8 af = *(const short8*)&sA[(16 * w + l15) * LDA + 32 * ks + 8 * quad];
#pragma unroll
      for (int qs = 0; qs < 4; ++qs) {
        short8 bfv = *(const short8*)&sU[(16 * qs + l15) * LDA + 32 * ks + 8 * quad];
        s1[qs] = __builtin_amdgcn_mfma_f32_16x16x32_bf16(af, bfv, s1[qs], 0, 0, 0);
      }
    }

    // ---- softmax over q (all 64 cols) per m-row.
    // C layout: row = quad*4+rg (within wave's 16 rows), col = qs*16 + l15
    float pv[4][4];
#pragma unroll
    for (int rg = 0; rg < 4; ++rg) {
      float v0 = s1[0][rg], v1 = s1[1][rg], v2 = s1[2][rg], v3 = s1[3][rg];
      float mx = fmaxf(fmaxf(v0, v1), fmaxf(v2, v3));
#pragma unroll
      for (int m = 1; m <= 8; m <<= 1) mx = fmaxf(mx, __shfl_xor(mx, m, 64));
      const float c = 1.4426950408889634f;
      float e0 = exp2f((v0 - mx) * c), e1 = exp2f((v1 - mx) * c);
      float e2 = exp2f((v2 - mx) * c), e3 = exp2f((v3 - mx) * c);
      float sm = e0 + e1 + e2 + e3;
#pragma unroll
      for (int m = 1; m <= 8; m <<= 1) sm += __shfl_xor(sm, m, 64);
      float inv = 1.0f / sm;
      pv[0][rg] = e0 * inv; pv[1][rg] = e1 * inv;
      pv[2][rg] = e2 * inv; pv[3][rg] = e3 * inv;
    }
    // write P^T[q][m] (bf16): 4 consecutive m (= regs) per b64 write
#pragma unroll
    for (int qs = 0; qs < 4; ++qs) {
      ushort4 h = make_ushort4(f2bf(pv[qs][0]), f2bf(pv[qs][1]),
                               f2bf(pv[qs][2]), f2bf(pv[qs][3]));
      *(ushort4*)&sP[(16 * qs + l15) * LDP + 16 * w + 4 * quad] = h;
    }
    __syncthreads();

    // ---- GEMM2: c[q][d] += sum_m P^T[q][m] * C[m][d]; wave w owns d 32w..32w+31
#pragma unroll
    for (int ks = 0; ks < 2; ++ks) {
      short8 pa[4];
#pragma unroll
      for (int qs = 0; qs < 4; ++qs)
        pa[qs] = *(const short8*)&sP[(16 * qs + l15) * LDP + 32 * ks + 8 * quad];
#pragma unroll
      for (int ds = 0; ds < 2; ++ds) {
        int d = l15 + 16 * (2 * w + ds);
        union { unsigned short u[8]; short8 v; } bb;
#pragma unroll
        for (int j = 0; j < 8; ++j)
          bb.u[j] = sC[(32 * ks + 8 * quad + j) * LDA + d];
#pragma unroll
        for (int qs = 0; qs < 4; ++qs)
          acc[ds][qs] = __builtin_amdgcn_mfma_f32_16x16x32_bf16(pa[qs], bb.v, acc[ds][qs], 0, 0, 0);
      }
    }
  }

  // epilogue: q = qs*16 + quad*4 + rg, d = l15 + 16*(2w+ds)
  if (use_atomic) {
#pragma unroll
    for (int ds = 0; ds < 2; ++ds)
#pragma unroll
      for (int qs = 0; qs < 4; ++qs)
#pragma unroll
        for (int rg = 0; rg < 4; ++rg) {
          int q = qs * 16 + quad * 4 + rg;
          int d = l15 + 16 * (2 * w + ds);
          atomicAdd(&dst[((size_t)b * Q_ + q) * D_ + d], acc[ds][qs][rg]);
        }
  } else {
    float* pp = dst + (((size_t)ch * B_ + b) * Q_) * D_;
#pragma unroll
    for (int ds = 0; ds < 2; ++ds)
#pragma unroll
      for (int qs = 0; qs < 4; ++qs)
#pragma unroll
        for (int rg = 0; rg < 4; ++rg) {
          int q = qs * 16 + quad * 4 + rg;
          int d = l15 + 16 * (2 * w + ds);
          pp[q * D_ + d] = acc[ds][qs][rg];
        }
  }
}

// out[b,q,d] = u[b,q,:]·H[:,d] + sum_ch partial[ch,b,q,d]
// chunks==0: write only u·H (init for atomic path)
__global__ __launch_bounds__(128) void memn2n_reduce(
    const float* __restrict__ U, const float* __restrict__ H,
    const float* __restrict__ part, float* __restrict__ out, int chunks) {
  int bq = blockIdx.x;
  int b = bq >> 6, q = bq & 63;
  int d = threadIdx.x;
  __shared__ float su[D_];
  size_t row = ((size_t)b * Q_ + q) * D_;
  su[d] = U[row + d];
  __syncthreads();
  float acc = 0.f;
#pragma unroll 16
  for (int e = 0; e < D_; ++e) acc = fmaf(su[e], H[e * D_ + d], acc);
  for (int ch = 0; ch < chunks; ++ch)
    acc += part[(((size_t)ch * B_ + b) * Q_ + q) * D_ + d];
  out[row + d] = acc;
}

extern "C" void kernel_launch(void* const* d_in, const int* in_sizes, int n_in,
                              void* d_out, int out_size, void* d_ws, size_t ws_size,
                              hipStream_t stream) {
  const float* A  = (const float*)d_in[0];
  const float* U  = (const float*)d_in[1];
  const float* Cc = (const float*)d_in[2];
  const float* H  = (const float*)d_in[3];
  float* out = (float*)d_out;

  const int CH = 16;
  size_t need = (size_t)CH * B_ * Q_ * D_ * sizeof(float);
  if (ws_size >= need) {
    float* part = (float*)d_ws;
    memn2n_main<<<B_ * CH, 256, 0, stream>>>(A, U, Cc, part, CH, 0);
    memn2n_reduce<<<B_ * Q_, 128, 0, stream>>>(U, H, part, out, CH);
  } else {
    // fallback: init out with u·H, then atomic-accumulate c
    memn2n_reduce<<<B_ * Q_, 128, 0, stream>>>(U, H, nullptr, out, 0);
    memn2n_main<<<B_ * 8, 256, 0, stream>>>(A, U, Cc, out, 8, 1);
  }
}